// Round 9
// baseline (53.348 us; speedup 1.0000x reference)
//
#include <hip/hip_runtime.h>
#include <hip/hip_bf16.h>

typedef float f32x4 __attribute__((ext_vector_type(4)));
typedef short bf16x8 __attribute__((ext_vector_type(8)));
typedef const __attribute__((address_space(1))) unsigned gas_u32;
typedef __attribute__((address_space(3))) unsigned las_u32;

__device__ __forceinline__ unsigned pk2(float lo, float hi) {
  union { __hip_bfloat162 h2; unsigned u; } c;
  c.h2 = __float22bfloat162_rn(make_float2(lo, hi));  // v_cvt_pk_bf16_f32
  return c.u;
}
__device__ __forceinline__ ushort f2bf1(float f) {
  union { __hip_bfloat16 h; ushort u; } c;
  c.h = __float2bfloat16(f);
  return c.u;
}

// ws layout: [0,128K) wpk bf16 A-frags; [128K,+2K) biasf f32;
//            [136K, 136K+256K) latf f32 pixel-major swizzled (4 batches x 64KB)
// latf[b] byte off pix*256 + ((16q)^((pix&7)<<4)) = ch 4q..4q+3 f32
__global__ void pack_all(const float* __restrict__ W0, const float* __restrict__ W1,
                         const float* __restrict__ W2, const float* __restrict__ W3,
                         const float* __restrict__ b0, const float* __restrict__ b1,
                         const float* __restrict__ b2, const float* __restrict__ b3,
                         const float* __restrict__ lat,
                         ushort* __restrict__ wpk, float* __restrict__ biasf,
                         float* __restrict__ latf) {
  int t = blockIdx.x * 256 + threadIdx.x;
  if (t < 8192) {
    int lane = t & 63, kt = (t >> 6) & 3, jt = (t >> 8) & 7, layer = t >> 11;
    const float* W = layer == 0 ? W0 : layer == 1 ? W1 : layer == 2 ? W2 : W3;
    int K = (layer == 0) ? 127 : 128;
    int g = lane >> 4, r = lane & 15;
    bf16x8 pk;
#pragma unroll
    for (int i = 0; i < 8; i++) {
      int k = kt * 32 + 8 * g + i;
      pk[i] = (short)((k < K) ? f2bf1(W[k * 128 + jt * 16 + r]) : (ushort)0);
    }
    *(bf16x8*)(wpk + ((t >> 11) * 32 + (jt * 4 + kt)) * 512 + lane * 8) = pk;
  } else if (t < 8192 + 16384) {
    int t2 = t - 8192;
    int q = t2 & 15, pix = (t2 >> 4) & 255, b = t2 >> 12;
    f32x4 v;
#pragma unroll
    for (int i = 0; i < 4; i++) v[i] = lat[(b * 64 + 4 * q + i) * 256 + pix];
    *(f32x4*)((char*)latf + b * 65536 + pix * 256 + ((16 * q) ^ ((pix & 7) << 4))) = v;
  } else if (t < 8192 + 16384 + 512) {
    int t3 = t - (8192 + 16384);
    int layer = t3 >> 7, j = t3 & 127;
    const float* b = layer == 0 ? b0 : layer == 1 ? b1 : layer == 2 ? b2 : b3;
    biasf[t3] = b[j];
  }
}

__global__ __launch_bounds__(512, 4) void scene_fwd(
    const float* __restrict__ xyz, const float* __restrict__ latf,
    const ushort* __restrict__ wpk, const float* __restrict__ biasf,
    const float* __restrict__ wa, const float* __restrict__ ba,
    float* __restrict__ out) {
  // 64 KB LDS. Phase A: f32 latent tile [0,64K) via global_load_lds (swizzle
  // pre-applied). Phase B: 4 h-tiles h[64 pts][128 ch] bf16 (16 KB each),
  // fully overlapping the latent region. 256 points/block, 512 threads.
  // Feature: threads 0-255 gather latents (ch 0-63, f32 -> no unpack) for
  // point tid; threads 256-511 compute PE (ch 64-127) for point tid-256.
  // MLP: wave w -> tile (w>>1), j-half (w&1); acc[4][4] = 64 f32 in AGPR;
  // 64 VGPR + 64 AGPR = 128 -> 16 waves/CU tier (2 blocks/CU by LDS).
  __shared__ char smem[65536];
  const int tid = threadIdx.x;
  const int wave = tid >> 6, lane = tid & 63;
  const int g = lane >> 4, r = lane & 15;
  const int p0 = blockIdx.x * 256;
  const int batch = blockIdx.x >> 8;  // 256 blocks per batch

  // ---- hoisted xyz load (latency hides under the stage) ----
  const int t2 = tid & 255;
  const int p = p0 + t2;
  const float X = xyz[3 * p + 0], Y = xyz[3 * p + 1], Z = xyz[3 * p + 2];

  // ---- stage f32 latent tile: direct global->LDS DMA, linear ----
  {
    const char* src = (const char*)latf + batch * 65536;
#pragma unroll
    for (int i = 0; i < 8; i++) {
      const int off = (i * 8 + wave) * 1024;
      __builtin_amdgcn_global_load_lds((gas_u32*)(src + off + lane * 16),
                                       (las_u32*)(smem + off), 16, 0, 0);
    }
  }
  __syncthreads();  // vmcnt drained before barrier

  // ---- per-point features into registers ----
  uint4 fr[8];  // this thread's 64 channels, bf16-packed
  if (tid < 256) {
    float gx = (X + 1.f) * 8.f - 0.5f;
    float gy = (Z + 1.f) * 8.f - 0.5f;
    float x0f = floorf(gx), y0f = floorf(gy);
    float fx = gx - x0f, fy = gy - y0f;
    int ix0 = (int)x0f, iy0 = (int)y0f;
    int ix1 = ix0 + 1, iy1 = iy0 + 1;
    float vx0 = (ix0 >= 0 && ix0 <= 15) ? 1.f : 0.f;
    float vx1 = (ix1 >= 0 && ix1 <= 15) ? 1.f : 0.f;
    float vy0 = (iy0 >= 0 && iy0 <= 15) ? 1.f : 0.f;
    float vy1 = (iy1 >= 0 && iy1 <= 15) ? 1.f : 0.f;
    int cx0 = min(max(ix0, 0), 15), cx1 = min(max(ix1, 0), 15);
    int cy0 = min(max(iy0, 0), 15), cy1 = min(max(iy1, 0), 15);
    float w00 = (1.f - fx) * (1.f - fy) * vx0 * vy0;
    float w01 = (1.f - fx) * fy * vx0 * vy1;
    float w10 = fx * (1.f - fy) * vx1 * vy0;
    float w11 = fx * fy * vx1 * vy1;
    int px00 = cy0 * 16 + cx0, px01 = cy1 * 16 + cx0;
    int px10 = cy0 * 16 + cx1, px11 = cy1 * 16 + cx1;
    int o00 = px00 * 256, s00 = (px00 & 7) << 4;
    int o01 = px01 * 256, s01 = (px01 & 7) << 4;
    int o10 = px10 * 256, s10 = (px10 & 7) << 4;
    int o11 = px11 * 256, s11 = (px11 & 7) << 4;
#pragma unroll
    for (int gr = 0; gr < 8; gr++) {
      float f[8];
#pragma unroll
      for (int u = 0; u < 2; u++) {
        const int off = 32 * gr + 16 * u;
        f32x4 c00 = *(const f32x4*)(smem + o00 + (off ^ s00));
        f32x4 c01 = *(const f32x4*)(smem + o01 + (off ^ s01));
        f32x4 c10 = *(const f32x4*)(smem + o10 + (off ^ s10));
        f32x4 c11 = *(const f32x4*)(smem + o11 + (off ^ s11));
#pragma unroll
        for (int i = 0; i < 4; i++)
          f[4 * u + i] = w00 * c00[i] + w01 * c01[i] + w10 * c10[i] + w11 * c11[i];
      }
      fr[gr].x = pk2(f[0], f[1]); fr[gr].y = pk2(f[2], f[3]);
      fr[gr].z = pk2(f[4], f[5]); fr[gr].w = pk2(f[6], f[7]);
    }
  } else {
    // PE pair-on-the-fly (no feat[64] buffer)
    float lcx = (X + 1.f) * 8.f; lcx = lcx - rintf(lcx - 0.5f); lcx = lcx * 2.f - 1.f;
    float lcz = (Z + 1.f) * 8.f; lcz = lcz - rintf(lcz - 0.5f); lcz = lcz * 2.f - 1.f;
    const float c0 = lcx, c1 = Y, c2 = lcz;
#pragma unroll
    for (int gr = 0; gr < 8; gr++) {
      unsigned* wo = &fr[gr].x;
#pragma unroll
      for (int q = 0; q < 4; q++) {
        float e[2];
#pragma unroll
        for (int h = 0; h < 2; h++) {
          const int idx = 8 * gr + 2 * q + h;
          float v;
          if (idx == 0) v = c0;
          else if (idx == 1) v = c1;
          else if (idx == 2) v = c2;
          else if (idx == 63) v = 0.f;
          else if (idx < 33) {
            const int s = idx - 3;
            const int d = s % 3;
            const float cc = d == 0 ? c0 : d == 1 ? c1 : c2;
            v = __sinf(cc * (float)(1 << (s / 3)));
          } else {
            const int s = idx - 33;
            const int d = s % 3;
            const float cc = d == 0 ? c0 : d == 1 ? c1 : c2;
            v = __cosf(cc * (float)(1 << (s / 3)));
          }
          e[h] = v;
        }
        wo[q] = pk2(e[0], e[1]);
      }
    }
  }
  __syncthreads();  // all gathers done before latent tile is overwritten

  // ---- write h rows (swizzled) ----
  {
    const int tile = t2 >> 6, row = t2 & 63;
    char* rowp = smem + tile * 16384 + row * 256;
    const unsigned swz = (unsigned)((row & 7) << 4);
    const int base = (tid < 256) ? 0 : 128;
#pragma unroll
    for (int gr = 0; gr < 8; gr++)
      *(uint4*)(rowp + (((unsigned)(base + 16 * gr)) ^ swz)) = fr[gr];
  }
  __syncthreads();

  // ---- MLP, j-split: wave covers 64 points x 64 output channels ----
  const int tileM = wave >> 1;
  const int jh = wave & 1;
  char* hb = smem + tileM * 16384;
  f32x4 acc[4][4];
#pragma unroll 1
  for (int layer = 0; layer < 4; layer++) {
    const float* bias = biasf + layer * 128;
    const ushort* Aw = wpk + layer * 16384;
#pragma unroll
    for (int jt = 0; jt < 4; jt++) {
      f32x4 bf = *(const f32x4*)(bias + (jh * 4 + jt) * 16 + 4 * g);
#pragma unroll
      for (int pt = 0; pt < 4; pt++) acc[jt][pt] = bf;
    }
#pragma unroll
    for (int kt = 0; kt < 4; kt++) {
      bf16x8 Bf[4];
#pragma unroll
      for (int pt = 0; pt < 4; pt++) {
        const int pr = pt * 16 + r;
        Bf[pt] = *(const bf16x8*)(hb + pr * 256 +
                  (((unsigned)(kt * 64 + 16 * g)) ^ ((unsigned)((pr & 7) << 4))));
      }
      __builtin_amdgcn_s_setprio(1);
#pragma unroll
      for (int jt = 0; jt < 4; jt++) {
        bf16x8 Af = *(const bf16x8*)(Aw + ((jh * 4 + jt) * 4 + kt) * 512 + lane * 8);
#pragma unroll
        for (int pt = 0; pt < 4; pt++)
          acc[jt][pt] = __builtin_amdgcn_mfma_f32_16x16x32_bf16(Af, Bf[pt], acc[jt][pt], 0, 0, 0);
      }
      __builtin_amdgcn_s_setprio(0);
    }
    if (layer < 3) {
      __syncthreads();  // all reads of h complete before overwrite
#pragma unroll
      for (int jt = 0; jt < 4; jt++) {
#pragma unroll
        for (int pt = 0; pt < 4; pt++) {
          const int pr = pt * 16 + r;
          uint2 w;
          w.x = pk2(fmaxf(acc[jt][pt][0], 0.f), fmaxf(acc[jt][pt][1], 0.f));
          w.y = pk2(fmaxf(acc[jt][pt][2], 0.f), fmaxf(acc[jt][pt][3], 0.f));
          *(uint2*)(hb + pr * 256 +
                    (((unsigned)(32 * (jh * 4 + jt) + 8 * g)) ^ ((unsigned)((pr & 7) << 4)))) = w;
        }
      }
      __syncthreads();  // writes visible before next layer's reads
    }
  }

  // ---- alpha: partial over this wave's j-half, then cross-wave combine ----
  const float ba0 = ba[0];
  float part[4] = {0.f, 0.f, 0.f, 0.f};
#pragma unroll
  for (int jt = 0; jt < 4; jt++) {
    f32x4 wf = *(const f32x4*)(wa + (jh * 4 + jt) * 16 + 4 * g);
#pragma unroll
    for (int pt = 0; pt < 4; pt++) {
#pragma unroll
      for (int i = 0; i < 4; i++)
        part[pt] += fmaxf(acc[jt][pt][i], 0.f) * wf[i];
    }
  }
  __syncthreads();  // layer-3 h reads done everywhere; scr region is free
  float* scr = (float*)smem;  // 2 KB scratch
#pragma unroll
  for (int pt = 0; pt < 4; pt++) {
    float s = part[pt];
    s += __shfl_xor(s, 16, 64);
    s += __shfl_xor(s, 32, 64);
    if (lane < 16) scr[(tileM * 2 + jh) * 64 + pt * 16 + lane] = s;
  }
  __syncthreads();
  if (jh == 0 && lane < 16) {
#pragma unroll
    for (int pt = 0; pt < 4; pt++) {
      const int idx = pt * 16 + lane;
      out[p0 + tileM * 64 + idx] =
          scr[(tileM * 2) * 64 + idx] + scr[(tileM * 2 + 1) * 64 + idx] + ba0;
    }
  }
}

extern "C" void kernel_launch(void* const* d_in, const int* in_sizes, int n_in,
                              void* d_out, int out_size, void* d_ws, size_t ws_size,
                              hipStream_t stream) {
  const float* xyz = (const float*)d_in[0];
  const float* lat = (const float*)d_in[1];
  const float* W0 = (const float*)d_in[2];
  const float* b0 = (const float*)d_in[3];
  const float* W1 = (const float*)d_in[4];
  const float* b1 = (const float*)d_in[5];
  const float* W2 = (const float*)d_in[6];
  const float* b2 = (const float*)d_in[7];
  const float* W3 = (const float*)d_in[8];
  const float* b3 = (const float*)d_in[9];
  const float* wa = (const float*)d_in[10];
  const float* ba = (const float*)d_in[11];
  float* out = (float*)d_out;
  ushort* wpk = (ushort*)d_ws;                      // 128 KB packed weights
  float* biasf = (float*)((char*)d_ws + 131072);    // 2 KB biases
  float* latf = (float*)((char*)d_ws + 139264);     // 256 KB packed f32 latents

  pack_all<<<98, 256, 0, stream>>>(W0, W1, W2, W3, b0, b1, b2, b3, lat,
                                   wpk, biasf, latf);
  scene_fwd<<<1024, 512, 0, stream>>>(xyz, latf, wpk, biasf, wa, ba, out);
}